// Round 2
// baseline (2449.610 us; speedup 1.0000x reference)
//
#include <hip/hip_runtime.h>
#include <cstdint>
#include <cstddef>

#define HH 128
#define SLOPE 0.01f

__device__ __forceinline__ float lrelu(float x) { return x >= 0.f ? x : SLOPE * x; }

// ---------------- degree / norm precompute ----------------

__global__ __launch_bounds__(256) void deg_kernel(const int* __restrict__ dst,
                                                  float* __restrict__ deg, int nE) {
  int e = blockIdx.x * 256 + threadIdx.x;
  if (e < nE) atomicAdd(&deg[dst[e]], 1.0f);
}

__global__ __launch_bounds__(256) void dinv_kernel(const float* __restrict__ deg,
                                                   float* __restrict__ dinv, int n) {
  int i = blockIdx.x * 256 + threadIdx.x;
  if (i < n) dinv[i] = rsqrtf(deg[i] + 1.0f);
}

__global__ __launch_bounds__(256) void norm_kernel(const int* __restrict__ src,
                                                   const int* __restrict__ dst,
                                                   const float* __restrict__ dinv,
                                                   float* __restrict__ norm, int nE) {
  int e = blockIdx.x * 256 + threadIdx.x;
  if (e < nE) norm[e] = dinv[src[e]] * dinv[dst[e]];
}

// ---------------- GEMM: [nrows,128] @ [128,128], all fp32 ----------------
// 64-row x 128-col tile per 256-thread block; 4x8 micro-tile per thread.
// LDS: A tile fp32 (32KB) + W half-tile fp32 (32KB, staged twice) = 64KB.

template <int BIAS, int LEAKY, int RES>
__global__ __launch_bounds__(256) void gemm128(const float* __restrict__ A,
                                               const float* __restrict__ W,
                                               const float* __restrict__ bias,
                                               const float* __restrict__ res,
                                               float* __restrict__ out, int nrows) {
  __shared__ __align__(16) float Al[64 * HH];
  __shared__ __align__(16) float Wl[64 * HH];
  const int tid = threadIdx.x;
  const int row0 = blockIdx.x * 64;

  // stage A tile (zero-fill out-of-range rows)
  for (int i = tid; i < 2048; i += 256) {  // 64 rows x 32 chunks of 4 floats
    int r = i >> 5, c = (i & 31) << 2;
    int gr = row0 + r;
    float4 v = make_float4(0.f, 0.f, 0.f, 0.f);
    if (gr < nrows) v = *(const float4*)(A + (size_t)gr * HH + c);
    *(float4*)&Al[r * HH + c] = v;
  }

  const int tx = tid & 15, ty = tid >> 4;
  const int c0 = tx << 3, r0 = ty << 2;
  float acc[4][8];
#pragma unroll
  for (int i = 0; i < 4; ++i)
#pragma unroll
    for (int j = 0; j < 8; ++j) acc[i][j] = 0.f;

#pragma unroll
  for (int h = 0; h < 2; ++h) {
    if (h) __syncthreads();  // wait for previous compute before overwriting Wl
    // stage W rows [h*64, h*64+64)
    for (int i = tid; i < 2048; i += 256) {
      int r = i >> 5, c = (i & 31) << 2;
      *(float4*)&Wl[r * HH + c] = *(const float4*)(W + (size_t)(h * 64 + r) * HH + c);
    }
    __syncthreads();
    const int kbase = h * 64;
#pragma unroll 2
    for (int k = 0; k < 64; k += 4) {
      float4 a[4];
#pragma unroll
      for (int i = 0; i < 4; ++i)
        a[i] = *(const float4*)&Al[(r0 + i) * HH + kbase + k];
#pragma unroll
      for (int kk = 0; kk < 4; ++kk) {
        const float* bp = &Wl[(k + kk) * HH + c0];
        float4 b0 = *(const float4*)bp;
        float4 b1 = *(const float4*)(bp + 4);
        float bb[8] = {b0.x, b0.y, b0.z, b0.w, b1.x, b1.y, b1.z, b1.w};
#pragma unroll
        for (int i = 0; i < 4; ++i) {
          float av = (&a[i].x)[kk];
#pragma unroll
          for (int j = 0; j < 8; ++j) acc[i][j] = fmaf(av, bb[j], acc[i][j]);
        }
      }
    }
  }

  float bv[8];
  if (BIAS) {
#pragma unroll
    for (int j = 0; j < 8; ++j) bv[j] = bias[c0 + j];
  }
#pragma unroll
  for (int i = 0; i < 4; ++i) {
    int gr = row0 + r0 + i;
    if (gr < nrows) {
      float v[8];
#pragma unroll
      for (int j = 0; j < 8; ++j) {
        float t = acc[i][j];
        if (BIAS) t += bv[j];
        if (RES) t += res[(size_t)gr * HH + c0 + j];
        if (LEAKY) t = lrelu(t);
        v[j] = t;
      }
      float* op = out + (size_t)gr * HH + c0;
      *(float4*)op = *(const float4*)&v[0];
      *(float4*)(op + 4) = *(const float4*)&v[4];
    }
  }
}

// ---------------- edge scatter: agg[dst] += h[src] * norm ----------------
// 32 lanes per edge, float4 per lane.

__global__ __launch_bounds__(256) void scatter_kernel(const float* __restrict__ h,
                                                      const int* __restrict__ src,
                                                      const int* __restrict__ dst,
                                                      const float* __restrict__ norm,
                                                      float* __restrict__ agg, int nE) {
  int tid = blockIdx.x * 256 + threadIdx.x;
  int e = tid >> 5;
  if (e >= nE) return;
  int f = (tid & 31) << 2;
  int s = src[e], d = dst[e];
  float nv = norm[e];
  float4 hv = *(const float4*)(h + (size_t)s * HH + f);
  float* ap = agg + (size_t)d * HH + f;
  atomicAdd(ap + 0, hv.x * nv);
  atomicAdd(ap + 1, hv.y * nv);
  atomicAdd(ap + 2, hv.z * nv);
  atomicAdd(ap + 3, hv.w * nv);
}

// ---------------- combine: out = leaky(agg + h*dinv^2 + b (+res)) ----------------

__global__ __launch_bounds__(256) void combine_kernel(const float* __restrict__ agg,
                                                      const float* __restrict__ h,
                                                      const float* __restrict__ dinv,
                                                      const float* __restrict__ bias,
                                                      const float* __restrict__ res,
                                                      float* __restrict__ out, int n,
                                                      int hasres) {
  int tid = blockIdx.x * 256 + threadIdx.x;
  int row = tid >> 5;
  if (row >= n) return;
  int c = (tid & 31) << 2;
  float di = dinv[row], d2 = di * di;
  size_t idx = (size_t)row * HH + c;
  float4 a = *(const float4*)(agg + idx);
  float4 hv = *(const float4*)(h + idx);
  float4 b = *(const float4*)(bias + c);
  float4 o;
  o.x = a.x + hv.x * d2 + b.x;
  o.y = a.y + hv.y * d2 + b.y;
  o.z = a.z + hv.z * d2 + b.z;
  o.w = a.w + hv.w * d2 + b.w;
  if (hasres) {
    float4 r = *(const float4*)(res + idx);
    o.x += r.x; o.y += r.y; o.z += r.z; o.w += r.w;
  }
  o.x = lrelu(o.x); o.y = lrelu(o.y); o.z = lrelu(o.z); o.w = lrelu(o.w);
  *(float4*)(out + idx) = o;
}

// ---------------- interp: out = 0.5*(h3 + gen) ----------------

__global__ __launch_bounds__(256) void interp_kernel(const float* __restrict__ h3,
                                                     const float* __restrict__ gen,
                                                     float* __restrict__ out, int n4) {
  int i = blockIdx.x * 256 + threadIdx.x;
  if (i >= n4) return;
  float4 h = ((const float4*)h3)[i];
  float4 g = ((const float4*)gen)[i];
  float4 o;
  o.x = 0.5f * (h.x + g.x);
  o.y = 0.5f * (h.y + g.y);
  o.z = 0.5f * (h.z + g.z);
  o.w = 0.5f * (h.w + g.w);
  ((float4*)out)[i] = o;
}

// ---------------- launcher ----------------

extern "C" void kernel_launch(void* const* d_in, const int* in_sizes, int n_in,
                              void* d_out, int out_size, void* d_ws, size_t ws_size,
                              hipStream_t stream) {
  const float* x   = (const float*)d_in[0];
  const int* ei    = (const int*)d_in[1];
  const float* gen = (const float*)d_in[2];
  const float* Wc1 = (const float*)d_in[3];
  const float* bc1 = (const float*)d_in[4];
  const float* Wc2 = (const float*)d_in[5];
  const float* bc2 = (const float*)d_in[6];
  const float* Wm1 = (const float*)d_in[7];
  const float* bm1 = (const float*)d_in[8];
  const float* Wm2 = (const float*)d_in[9];
  const float* bm2 = (const float*)d_in[10];
  const float* Wp1 = (const float*)d_in[11];
  const float* bp1 = (const float*)d_in[12];
  const float* Wp2 = (const float*)d_in[13];
  const float* bp2 = (const float*)d_in[14];

  const int N = in_sizes[0] / HH;
  const int E = in_sizes[1] / 2;
  const int* src = ei;
  const int* dst = ei + E;

  float* ws = (float*)d_ws;
  size_t off = 0;
  float* dinv = ws + off; off += (size_t)((N + 15) & ~15);
  float* norm = ws + off; off += (size_t)((E + 15) & ~15);
  float* hA   = ws + off; off += (size_t)N * HH;
  float* agg  = ws + off; off += (size_t)N * HH;
  float* hOut = (float*)d_out;  // reuse output buffer as the 3rd [N,128] scratch

  const int gblocks = (N + 63) / 64;
  const int eblocks = (E + 255) / 256;
  const int nblocks = (N + 255) / 256;
  const int sblocks = (int)(((size_t)E * 32 + 255) / 256);
  const int cblocks = (int)(((size_t)N * 32 + 255) / 256);
  const int iblocks = (int)(((size_t)N * 32 + 255) / 256);

  // degree / dinv / per-edge norm (deg accumulated in agg's first N floats)
  hipMemsetAsync(agg, 0, (size_t)N * sizeof(float), stream);
  deg_kernel<<<eblocks, 256, 0, stream>>>(dst, agg, E);
  dinv_kernel<<<nblocks, 256, 0, stream>>>(agg, dinv, N);
  norm_kernel<<<eblocks, 256, 0, stream>>>(src, dst, dinv, norm, E);

  // conv1: hOut = leaky(agg(x@Wc1) + self + bc1)
  gemm128<0, 0, 0><<<gblocks, 256, 0, stream>>>(x, Wc1, nullptr, nullptr, hA, N);
  hipMemsetAsync(agg, 0, (size_t)N * HH * sizeof(float), stream);
  scatter_kernel<<<sblocks, 256, 0, stream>>>(hA, src, dst, norm, agg, E);
  combine_kernel<<<cblocks, 256, 0, stream>>>(agg, hA, dinv, bc1, nullptr, hOut, N, 0);

  // conv2: hOut = leaky(agg(hOut@Wc2) + self + bc2 + hOut)
  gemm128<0, 0, 0><<<gblocks, 256, 0, stream>>>(hOut, Wc2, nullptr, nullptr, hA, N);
  hipMemsetAsync(agg, 0, (size_t)N * HH * sizeof(float), stream);
  scatter_kernel<<<sblocks, 256, 0, stream>>>(hA, src, dst, norm, agg, E);
  combine_kernel<<<cblocks, 256, 0, stream>>>(agg, hA, dinv, bc2, hOut, hOut, N, 1);

  // MLP: agg = h3 = leaky(leaky(hOut@Wm1+bm1)@Wm2 + bm2 + hOut)
  gemm128<1, 1, 0><<<gblocks, 256, 0, stream>>>(hOut, Wm1, bm1, nullptr, hA, N);
  gemm128<1, 1, 1><<<gblocks, 256, 0, stream>>>(hA, Wm2, bm2, hOut, agg, N);

  // interp: hA = 0.5*h3 + 0.5*gen
  interp_kernel<<<iblocks, 256, 0, stream>>>(agg, gen, hA, N * 32);

  // proj: d_out = leaky(leaky(hA@Wp1+bp1)@Wp2 + bp2)
  gemm128<1, 1, 0><<<gblocks, 256, 0, stream>>>(hA, Wp1, bp1, nullptr, hOut, N);
  gemm128<1, 1, 0><<<gblocks, 256, 0, stream>>>(hOut, Wp2, bp2, nullptr, hOut, N);
}

// Round 3
// 575.619 us; speedup vs baseline: 4.2556x; 4.2556x over previous
//
#include <hip/hip_runtime.h>
#include <cstdint>
#include <cstddef>

#define HH 128
#define SLOPE 0.01f

__device__ __forceinline__ float lrelu(float x) { return x >= 0.f ? x : SLOPE * x; }

// ---------------- CSR build ----------------

__global__ __launch_bounds__(256) void count_kernel(const int* __restrict__ dst,
                                                    int* __restrict__ cnt, int nE) {
  int e = blockIdx.x * 256 + threadIdx.x;
  if (e < nE) atomicAdd(&cnt[dst[e]], 1);
}

// Single-block exclusive prefix sum over cnt[0..n) -> rowptr; also dinv = rsqrt(cnt+1)
// and resets cnt to 0 (reused as fill cursor). rowptr[n] = total.
__global__ __launch_bounds__(1024) void scan_kernel(int* __restrict__ cnt,
                                                    int* __restrict__ rowptr,
                                                    float* __restrict__ dinv, int n) {
  __shared__ int wsum[16];
  __shared__ int carry_s;
  const int tid = threadIdx.x;
  const int lane = tid & 63, wid = tid >> 6;
  if (tid == 0) carry_s = 0;
  __syncthreads();
  for (int base = 0; base < n; base += 1024) {
    int i = base + tid;
    int v = (i < n) ? cnt[i] : 0;
    // wave-level inclusive scan (64 lanes)
    int x = v;
#pragma unroll
    for (int off = 1; off < 64; off <<= 1) {
      int y = __shfl_up(x, off, 64);
      if (lane >= off) x += y;
    }
    if (lane == 63) wsum[wid] = x;
    __syncthreads();
    if (tid == 0) {
      int s = 0;
#pragma unroll
      for (int w = 0; w < 16; ++w) { int t = wsum[w]; wsum[w] = s; s += t; }
    }
    __syncthreads();
    int incl = x + wsum[wid];          // inclusive within this chunk
    int carry = carry_s;
    __syncthreads();                    // everyone read carry before update
    if (i < n) {
      rowptr[i] = carry + incl - v;     // exclusive prefix
      dinv[i] = rsqrtf((float)v + 1.0f);
      cnt[i] = 0;                       // reset cursor
    }
    if (tid == 1023) carry_s = carry + incl;
    __syncthreads();
  }
  if (tid == 0) rowptr[n] = carry_s;
}

__global__ __launch_bounds__(256) void fill_kernel(const int* __restrict__ src,
                                                   const int* __restrict__ dst,
                                                   const int* __restrict__ rowptr,
                                                   int* __restrict__ cursor,
                                                   const float* __restrict__ dinv,
                                                   int* __restrict__ csr_src,
                                                   float* __restrict__ csr_norm, int nE) {
  int e = blockIdx.x * 256 + threadIdx.x;
  if (e >= nE) return;
  int d = dst[e], s = src[e];
  int pos = rowptr[d] + atomicAdd(&cursor[d], 1);
  csr_src[pos] = s;
  csr_norm[pos] = dinv[s] * dinv[d];
}

// ---------------- fused aggregate + self-loop + bias (+res) + leaky ----------------
// One 64-lane wave per dst node; each lane owns a float2 of the 128 features.

template <int RES>
__global__ __launch_bounds__(256) void agg_kernel(const float* __restrict__ h,
                                                  const int* __restrict__ rowptr,
                                                  const int* __restrict__ csr_src,
                                                  const float* __restrict__ csr_norm,
                                                  const float* __restrict__ dinv,
                                                  const float* __restrict__ bias,
                                                  const float* __restrict__ res,
                                                  float* __restrict__ out, int n) {
  int node = blockIdx.x * 4 + (threadIdx.x >> 6);
  if (node >= n) return;
  int lane = threadIdx.x & 63;
  int c = lane << 1;
  int j = rowptr[node], end = rowptr[node + 1];
  float ax = 0.f, ay = 0.f;
  // 2x unrolled edge loop for load latency
  for (; j + 2 <= end; j += 2) {
    int s0 = csr_src[j], s1 = csr_src[j + 1];
    float n0 = csr_norm[j], n1 = csr_norm[j + 1];
    float2 h0 = *(const float2*)(h + (size_t)s0 * HH + c);
    float2 h1 = *(const float2*)(h + (size_t)s1 * HH + c);
    ax = fmaf(h0.x, n0, ax); ay = fmaf(h0.y, n0, ay);
    ax = fmaf(h1.x, n1, ax); ay = fmaf(h1.y, n1, ay);
  }
  if (j < end) {
    int s0 = csr_src[j];
    float n0 = csr_norm[j];
    float2 h0 = *(const float2*)(h + (size_t)s0 * HH + c);
    ax = fmaf(h0.x, n0, ax); ay = fmaf(h0.y, n0, ay);
  }
  float di = dinv[node], d2 = di * di;
  float2 hv = *(const float2*)(h + (size_t)node * HH + c);
  float2 b = *(const float2*)(bias + c);
  float ox = ax + hv.x * d2 + b.x;
  float oy = ay + hv.y * d2 + b.y;
  if (RES) {
    float2 r = *(const float2*)(res + (size_t)node * HH + c);
    ox += r.x; oy += r.y;
  }
  ox = lrelu(ox); oy = lrelu(oy);
  float2 o = make_float2(ox, oy);
  *(float2*)(out + (size_t)node * HH + c) = o;
}

// ---------------- GEMM: [nrows,128] @ [128,128], all fp32 ----------------
// 64-row x 128-col tile per 256-thread block; 4x8 micro-tile per thread.
// Row-local on A/res/out => in-place (out==A or out==res) is safe.

template <int BIAS, int LEAKY, int RES>
__global__ __launch_bounds__(256) void gemm128(const float* __restrict__ A,
                                               const float* __restrict__ W,
                                               const float* __restrict__ bias,
                                               const float* __restrict__ res,
                                               float* __restrict__ out, int nrows) {
  __shared__ __align__(16) float Al[64 * HH];
  __shared__ __align__(16) float Wl[64 * HH];
  const int tid = threadIdx.x;
  const int row0 = blockIdx.x * 64;

  for (int i = tid; i < 2048; i += 256) {  // 64 rows x 32 chunks of 4 floats
    int r = i >> 5, c = (i & 31) << 2;
    int gr = row0 + r;
    float4 v = make_float4(0.f, 0.f, 0.f, 0.f);
    if (gr < nrows) v = *(const float4*)(A + (size_t)gr * HH + c);
    *(float4*)&Al[r * HH + c] = v;
  }

  const int tx = tid & 15, ty = tid >> 4;
  const int c0 = tx << 3, r0 = ty << 2;
  float acc[4][8];
#pragma unroll
  for (int i = 0; i < 4; ++i)
#pragma unroll
    for (int j = 0; j < 8; ++j) acc[i][j] = 0.f;

#pragma unroll
  for (int h = 0; h < 2; ++h) {
    if (h) __syncthreads();
    for (int i = tid; i < 2048; i += 256) {
      int r = i >> 5, c = (i & 31) << 2;
      *(float4*)&Wl[r * HH + c] = *(const float4*)(W + (size_t)(h * 64 + r) * HH + c);
    }
    __syncthreads();
    const int kbase = h * 64;
#pragma unroll 2
    for (int k = 0; k < 64; k += 4) {
      float4 a[4];
#pragma unroll
      for (int i = 0; i < 4; ++i)
        a[i] = *(const float4*)&Al[(r0 + i) * HH + kbase + k];
#pragma unroll
      for (int kk = 0; kk < 4; ++kk) {
        const float* bp = &Wl[(k + kk) * HH + c0];
        float4 b0 = *(const float4*)bp;
        float4 b1 = *(const float4*)(bp + 4);
        float bb[8] = {b0.x, b0.y, b0.z, b0.w, b1.x, b1.y, b1.z, b1.w};
#pragma unroll
        for (int i = 0; i < 4; ++i) {
          float av = (&a[i].x)[kk];
#pragma unroll
          for (int j = 0; j < 8; ++j) acc[i][j] = fmaf(av, bb[j], acc[i][j]);
        }
      }
    }
  }

  float bv[8];
  if (BIAS) {
#pragma unroll
    for (int j = 0; j < 8; ++j) bv[j] = bias[c0 + j];
  }
#pragma unroll
  for (int i = 0; i < 4; ++i) {
    int gr = row0 + r0 + i;
    if (gr < nrows) {
      float v[8];
#pragma unroll
      for (int j = 0; j < 8; ++j) {
        float t = acc[i][j];
        if (BIAS) t += bv[j];
        if (RES) t += res[(size_t)gr * HH + c0 + j];
        if (LEAKY) t = lrelu(t);
        v[j] = t;
      }
      float* op = out + (size_t)gr * HH + c0;
      *(float4*)op = *(const float4*)&v[0];
      *(float4*)(op + 4) = *(const float4*)&v[4];
    }
  }
}

// ---------------- interp: out = 0.5*(h3 + gen), in-place safe ----------------

__global__ __launch_bounds__(256) void interp_kernel(const float* __restrict__ h3,
                                                     const float* __restrict__ gen,
                                                     float* __restrict__ out, int n4) {
  int i = blockIdx.x * 256 + threadIdx.x;
  if (i >= n4) return;
  float4 h = ((const float4*)h3)[i];
  float4 g = ((const float4*)gen)[i];
  float4 o;
  o.x = 0.5f * (h.x + g.x);
  o.y = 0.5f * (h.y + g.y);
  o.z = 0.5f * (h.z + g.z);
  o.w = 0.5f * (h.w + g.w);
  ((float4*)out)[i] = o;
}

// ---------------- launcher ----------------

extern "C" void kernel_launch(void* const* d_in, const int* in_sizes, int n_in,
                              void* d_out, int out_size, void* d_ws, size_t ws_size,
                              hipStream_t stream) {
  const float* x   = (const float*)d_in[0];
  const int* ei    = (const int*)d_in[1];
  const float* gen = (const float*)d_in[2];
  const float* Wc1 = (const float*)d_in[3];
  const float* bc1 = (const float*)d_in[4];
  const float* Wc2 = (const float*)d_in[5];
  const float* bc2 = (const float*)d_in[6];
  const float* Wm1 = (const float*)d_in[7];
  const float* bm1 = (const float*)d_in[8];
  const float* Wm2 = (const float*)d_in[9];
  const float* bm2 = (const float*)d_in[10];
  const float* Wp1 = (const float*)d_in[11];
  const float* bp1 = (const float*)d_in[12];
  const float* Wp2 = (const float*)d_in[13];
  const float* bp2 = (const float*)d_in[14];

  const int N = in_sizes[0] / HH;
  const int E = in_sizes[1] / 2;
  const int* src = ei;
  const int* dst = ei + E;

  char* ws = (char*)d_ws;
  size_t off = 0;
  auto alloc = [&](size_t bytes) { void* p = ws + off; off += (bytes + 255) & ~(size_t)255; return p; };
  float* dinv    = (float*)alloc((size_t)N * 4);
  int*   rowptr  = (int*)  alloc((size_t)(N + 1) * 4);
  int*   cursor  = (int*)  alloc((size_t)N * 4);
  int*   csr_src = (int*)  alloc((size_t)E * 4);
  float* csr_norm= (float*)alloc((size_t)E * 4);
  float* hA      = (float*)alloc((size_t)N * HH * 4);
  float* hOut = (float*)d_out;  // output buffer doubles as the 2nd [N,128] buffer

  const int gblocks = (N + 63) / 64;
  const int eblocks = (E + 255) / 256;
  const int ablocks = (N + 3) / 4;
  const int iblocks = (int)(((size_t)N * 32 + 255) / 256);

  // CSR build (also deg->dinv)
  hipMemsetAsync(cursor, 0, (size_t)N * 4, stream);
  count_kernel<<<eblocks, 256, 0, stream>>>(dst, cursor, E);
  scan_kernel<<<1, 1024, 0, stream>>>(cursor, rowptr, dinv, N);
  fill_kernel<<<eblocks, 256, 0, stream>>>(src, dst, rowptr, cursor, dinv, csr_src, csr_norm, E);

  // conv1: hOut = leaky(agg(x@Wc1) + self + bc1)
  gemm128<0, 0, 0><<<gblocks, 256, 0, stream>>>(x, Wc1, nullptr, nullptr, hA, N);
  agg_kernel<0><<<ablocks, 256, 0, stream>>>(hA, rowptr, csr_src, csr_norm, dinv, bc1, nullptr, hOut, N);

  // conv2: hOut = leaky(agg(hOut@Wc2) + self + bc2 + hOut)
  gemm128<0, 0, 0><<<gblocks, 256, 0, stream>>>(hOut, Wc2, nullptr, nullptr, hA, N);
  agg_kernel<1><<<ablocks, 256, 0, stream>>>(hA, rowptr, csr_src, csr_norm, dinv, bc2, hOut, hOut, N);

  // MLP: hA = h3 = leaky(leaky(hOut@Wm1+bm1)@Wm2 + bm2 + hOut)
  gemm128<1, 1, 0><<<gblocks, 256, 0, stream>>>(hOut, Wm1, bm1, nullptr, hA, N);
  gemm128<1, 1, 1><<<gblocks, 256, 0, stream>>>(hA, Wm2, bm2, hOut, hA, N);

  // interp (in-place): hA = 0.5*h3 + 0.5*gen
  interp_kernel<<<iblocks, 256, 0, stream>>>(hA, gen, hA, N * 32);

  // proj: d_out = leaky(leaky(hA@Wp1+bp1)@Wp2 + bp2)
  gemm128<1, 1, 0><<<gblocks, 256, 0, stream>>>(hA, Wp1, bp1, nullptr, hA, N);
  gemm128<1, 1, 0><<<gblocks, 256, 0, stream>>>(hA, Wp2, bp2, nullptr, hOut, N);
}

// Round 4
// 406.961 us; speedup vs baseline: 6.0193x; 1.4144x over previous
//
#include <hip/hip_runtime.h>
#include <cstdint>
#include <cstddef>

#define HH 128
#define SLOPE 0.01f

typedef __attribute__((ext_vector_type(8))) __bf16 bf16x8;
typedef __attribute__((ext_vector_type(4))) float f32x4;

__device__ __forceinline__ float lrelu(float x) { return x >= 0.f ? x : SLOPE * x; }
__device__ __forceinline__ unsigned short f2b(float f) {
  union { float f; unsigned u; } v; v.f = f;
  unsigned r = v.u + 0x7fffu + ((v.u >> 16) & 1u);  // round-to-nearest-even
  return (unsigned short)(r >> 16);
}
__device__ __forceinline__ float b2f(unsigned short u) {
  union { unsigned u; float f; } v; v.u = ((unsigned)u) << 16; return v.f;
}

// ---------------- CSR build ----------------

__global__ __launch_bounds__(256) void count_kernel(const int* __restrict__ dst,
                                                    int* __restrict__ cnt, int nE) {
  int e = blockIdx.x * 256 + threadIdx.x;
  if (e < nE) atomicAdd(&cnt[dst[e]], 1);
}

__global__ __launch_bounds__(1024) void scan_kernel(int* __restrict__ cnt,
                                                    int* __restrict__ rowptr,
                                                    float* __restrict__ dinv, int n) {
  __shared__ int wsum[16];
  __shared__ int carry_s;
  const int tid = threadIdx.x;
  const int lane = tid & 63, wid = tid >> 6;
  if (tid == 0) carry_s = 0;
  __syncthreads();
  for (int base = 0; base < n; base += 1024) {
    int i = base + tid;
    int v = (i < n) ? cnt[i] : 0;
    int x = v;
#pragma unroll
    for (int off = 1; off < 64; off <<= 1) {
      int y = __shfl_up(x, off, 64);
      if (lane >= off) x += y;
    }
    if (lane == 63) wsum[wid] = x;
    __syncthreads();
    if (tid == 0) {
      int s = 0;
#pragma unroll
      for (int w = 0; w < 16; ++w) { int t = wsum[w]; wsum[w] = s; s += t; }
    }
    __syncthreads();
    int incl = x + wsum[wid];
    int carry = carry_s;
    __syncthreads();
    if (i < n) {
      rowptr[i] = carry + incl - v;
      dinv[i] = rsqrtf((float)v + 1.0f);
      cnt[i] = 0;
    }
    if (tid == 1023) carry_s = carry + incl;
    __syncthreads();
  }
  if (tid == 0) rowptr[n] = carry_s;
}

__global__ __launch_bounds__(256) void fill_kernel(const int* __restrict__ src,
                                                   const int* __restrict__ dst,
                                                   const int* __restrict__ rowptr,
                                                   int* __restrict__ cursor,
                                                   const float* __restrict__ dinv,
                                                   int* __restrict__ csr_src,
                                                   float* __restrict__ csr_norm, int nE) {
  int e = blockIdx.x * 256 + threadIdx.x;
  if (e >= nE) return;
  int d = dst[e], s = src[e];
  int pos = rowptr[d] + atomicAdd(&cursor[d], 1);
  csr_src[pos] = s;
  csr_norm[pos] = dinv[s] * dinv[d];
}

// ---------------- weight pack: B-fragment order for mfma 16x16x32 ----------------
// packed[(t*8+c)*64 + lane][j] = W[t*32 + (lane>>4)*8 + j][c*16 + (lane&15)]

__global__ __launch_bounds__(256) void pack_kernel(const float* W0, const float* W1,
                                                   const float* W2, const float* W3,
                                                   const float* W4, const float* W5,
                                                   unsigned short* __restrict__ out) {
  const float* Ws[6] = {W0, W1, W2, W3, W4, W5};
  const float* W = Ws[blockIdx.y];
  int f = blockIdx.x * 256 + threadIdx.x;  // 0..16383
  int j = f & 7, L = (f >> 3) & 63, c = (f >> 9) & 7, t = f >> 12;
  int k = t * 32 + (L >> 4) * 8 + j;
  int n = c * 16 + (L & 15);
  out[(size_t)blockIdx.y * 16384 + f] = f2b(W[k * HH + n]);
}

// ---------------- MFMA GEMM: [nrows,128] @ [128,128] ----------------
// 256 threads = 4 waves; 64 rows/block (16 rows/wave), full 128 cols.
// A staged fp32->bf16 in 16KB LDS; B-frags read from packed global (L2-hit).

template <int BIAS, int LEAKY, int RES, int INTERP, int OUT_BF16>
__global__ __launch_bounds__(256) void gemm_mfma(const float* __restrict__ A,
                                                 const unsigned short* __restrict__ Wp,
                                                 const float* __restrict__ bias,
                                                 const float* __restrict__ res,
                                                 const float* __restrict__ gen,
                                                 void* __restrict__ outv, int nrows) {
  __shared__ __align__(16) unsigned short Al[64 * HH];
  const int tid = threadIdx.x;
  const int row0 = blockIdx.x * 64;

  for (int i = tid; i < 2048; i += 256) {
    int r = i >> 5, c = (i & 31) << 2;
    int gr = row0 + r;
    float4 v = make_float4(0.f, 0.f, 0.f, 0.f);
    if (gr < nrows) {
      v = *(const float4*)(A + (size_t)gr * HH + c);
      if (INTERP) {
        float4 g = *(const float4*)(gen + (size_t)gr * HH + c);
        v.x = 0.5f * (v.x + g.x); v.y = 0.5f * (v.y + g.y);
        v.z = 0.5f * (v.z + g.z); v.w = 0.5f * (v.w + g.w);
      }
    }
    ushort4 o;
    o.x = f2b(v.x); o.y = f2b(v.y); o.z = f2b(v.z); o.w = f2b(v.w);
    *(ushort4*)&Al[r * HH + c] = o;
  }
  __syncthreads();

  const int lane = tid & 63, wave = tid >> 6;
  const int m = lane & 15, quad = lane >> 4;
  const int arow = wave * 16 + m;

  f32x4 acc[8];
#pragma unroll
  for (int c = 0; c < 8; ++c) acc[c] = (f32x4){0.f, 0.f, 0.f, 0.f};

  const bf16x8* Wf = (const bf16x8*)Wp;
#pragma unroll
  for (int t = 0; t < 4; ++t) {
    bf16x8 a = *(const bf16x8*)&Al[arow * HH + t * 32 + quad * 8];
#pragma unroll
    for (int c = 0; c < 8; ++c) {
      bf16x8 b = Wf[(t * 8 + c) * 64 + lane];
      acc[c] = __builtin_amdgcn_mfma_f32_16x16x32_bf16(a, b, acc[c], 0, 0, 0);
    }
  }

#pragma unroll
  for (int c = 0; c < 8; ++c) {
    int col = c * 16 + m;
    float bv = BIAS ? bias[col] : 0.f;
#pragma unroll
    for (int g = 0; g < 4; ++g) {
      int row = row0 + wave * 16 + quad * 4 + g;
      if (row < nrows) {
        float v = acc[c][g] + bv;
        if (RES) v += res[(size_t)row * HH + col];
        if (LEAKY) v = lrelu(v);
        if (OUT_BF16) ((unsigned short*)outv)[(size_t)row * HH + col] = f2b(v);
        else ((float*)outv)[(size_t)row * HH + col] = v;
      }
    }
  }
}

// ---------------- fused aggregate (bf16 gather) + self + bias (+res) + leaky ----------------

template <int RES>
__global__ __launch_bounds__(256) void agg_kernel(const unsigned short* __restrict__ h,
                                                  const int* __restrict__ rowptr,
                                                  const int* __restrict__ csr_src,
                                                  const float* __restrict__ csr_norm,
                                                  const float* __restrict__ dinv,
                                                  const float* __restrict__ bias,
                                                  const float* __restrict__ res,
                                                  float* __restrict__ out, int n) {
  int node = blockIdx.x * 4 + (threadIdx.x >> 6);
  if (node >= n) return;
  int lane = threadIdx.x & 63;
  int c = lane << 1;
  int j = rowptr[node], end = rowptr[node + 1];
  float ax = 0.f, ay = 0.f;
  for (; j + 2 <= end; j += 2) {
    int s0 = csr_src[j], s1 = csr_src[j + 1];
    float n0 = csr_norm[j], n1 = csr_norm[j + 1];
    ushort2 r0 = *(const ushort2*)(h + (size_t)s0 * HH + c);
    ushort2 r1 = *(const ushort2*)(h + (size_t)s1 * HH + c);
    ax = fmaf(b2f(r0.x), n0, ax); ay = fmaf(b2f(r0.y), n0, ay);
    ax = fmaf(b2f(r1.x), n1, ax); ay = fmaf(b2f(r1.y), n1, ay);
  }
  if (j < end) {
    int s0 = csr_src[j];
    float n0 = csr_norm[j];
    ushort2 r0 = *(const ushort2*)(h + (size_t)s0 * HH + c);
    ax = fmaf(b2f(r0.x), n0, ax); ay = fmaf(b2f(r0.y), n0, ay);
  }
  float di = dinv[node], d2 = di * di;
  ushort2 hs = *(const ushort2*)(h + (size_t)node * HH + c);
  float2 b = *(const float2*)(bias + c);
  float ox = ax + b2f(hs.x) * d2 + b.x;
  float oy = ay + b2f(hs.y) * d2 + b.y;
  if (RES) {
    float2 r = *(const float2*)(res + (size_t)node * HH + c);
    ox += r.x; oy += r.y;
  }
  ox = lrelu(ox); oy = lrelu(oy);
  *(float2*)(out + (size_t)node * HH + c) = make_float2(ox, oy);
}

// ---------------- launcher ----------------

extern "C" void kernel_launch(void* const* d_in, const int* in_sizes, int n_in,
                              void* d_out, int out_size, void* d_ws, size_t ws_size,
                              hipStream_t stream) {
  const float* x   = (const float*)d_in[0];
  const int* ei    = (const int*)d_in[1];
  const float* gen = (const float*)d_in[2];
  const float* Wc1 = (const float*)d_in[3];
  const float* bc1 = (const float*)d_in[4];
  const float* Wc2 = (const float*)d_in[5];
  const float* bc2 = (const float*)d_in[6];
  const float* Wm1 = (const float*)d_in[7];
  const float* bm1 = (const float*)d_in[8];
  const float* Wm2 = (const float*)d_in[9];
  const float* bm2 = (const float*)d_in[10];
  const float* Wp1 = (const float*)d_in[11];
  const float* bp1 = (const float*)d_in[12];
  const float* Wp2 = (const float*)d_in[13];
  const float* bp2 = (const float*)d_in[14];

  const int N = in_sizes[0] / HH;
  const int E = in_sizes[1] / 2;
  const int* src = ei;
  const int* dst = ei + E;

  char* ws = (char*)d_ws;
  size_t off = 0;
  auto alloc = [&](size_t bytes) { void* p = ws + off; off += (bytes + 255) & ~(size_t)255; return p; };
  float* dinv            = (float*)alloc((size_t)N * 4);
  int*   rowptr          = (int*)  alloc((size_t)(N + 1) * 4);
  int*   cursor          = (int*)  alloc((size_t)N * 4);
  int*   csr_src         = (int*)  alloc((size_t)E * 4);
  float* csr_norm        = (float*)alloc((size_t)E * 4);
  unsigned short* h_bf   = (unsigned short*)alloc((size_t)N * HH * 2);
  float* f1              = (float*)alloc((size_t)N * HH * 4);
  unsigned short* packed = (unsigned short*)alloc((size_t)6 * 16384 * 2);
  float* f2 = (float*)d_out;  // output buffer doubles as fp32 scratch

  const int gblocks = (N + 63) / 64;
  const int eblocks = (E + 255) / 256;
  const int ablocks = (N + 3) / 4;

  // weight packing (6 weights x 16384 frag elements)
  pack_kernel<<<dim3(64, 6), 256, 0, stream>>>(Wc1, Wc2, Wm1, Wm2, Wp1, Wp2, packed);

  // CSR build (also deg->dinv)
  hipMemsetAsync(cursor, 0, (size_t)N * 4, stream);
  count_kernel<<<eblocks, 256, 0, stream>>>(dst, cursor, E);
  scan_kernel<<<1, 1024, 0, stream>>>(cursor, rowptr, dinv, N);
  fill_kernel<<<eblocks, 256, 0, stream>>>(src, dst, rowptr, cursor, dinv, csr_src, csr_norm, E);

  // conv1: h_bf = bf16(x @ Wc1); f1 = leaky(agg + self + bc1)
  gemm_mfma<0, 0, 0, 0, 1><<<gblocks, 256, 0, stream>>>(x, packed + 0 * 16384, nullptr, nullptr, nullptr, h_bf, N);
  agg_kernel<0><<<ablocks, 256, 0, stream>>>(h_bf, rowptr, csr_src, csr_norm, dinv, bc1, nullptr, f1, N);

  // conv2: h_bf = bf16(f1 @ Wc2); f1 = leaky(agg + self + bc2 + f1)
  gemm_mfma<0, 0, 0, 0, 1><<<gblocks, 256, 0, stream>>>(f1, packed + 1 * 16384, nullptr, nullptr, nullptr, h_bf, N);
  agg_kernel<1><<<ablocks, 256, 0, stream>>>(h_bf, rowptr, csr_src, csr_norm, dinv, bc2, f1, f1, N);

  // MLP: f2 = leaky(f1@Wm1+bm1); f1 = h3 = leaky(f2@Wm2+bm2+f1)
  gemm_mfma<1, 1, 0, 0, 0><<<gblocks, 256, 0, stream>>>(f1, packed + 2 * 16384, bm1, nullptr, nullptr, f2, N);
  gemm_mfma<1, 1, 1, 0, 0><<<gblocks, 256, 0, stream>>>(f2, packed + 3 * 16384, bm2, f1, nullptr, f1, N);

  // proj with fused interp: f2 = leaky((0.5*(f1+gen))@Wp1+bp1); d_out = leaky(f2@Wp2+bp2)
  gemm_mfma<1, 1, 0, 1, 0><<<gblocks, 256, 0, stream>>>(f1, packed + 4 * 16384, bp1, nullptr, gen, f2, N);
  gemm_mfma<1, 1, 0, 0, 0><<<gblocks, 256, 0, stream>>>(f2, packed + 5 * 16384, bp2, nullptr, nullptr, f2, N);
}

// Round 5
// 342.286 us; speedup vs baseline: 7.1566x; 1.1889x over previous
//
#include <hip/hip_runtime.h>
#include <cstdint>
#include <cstddef>

#define HH 128
#define SLOPE 0.01f

typedef __attribute__((ext_vector_type(8))) __bf16 bf16x8;
typedef __attribute__((ext_vector_type(4))) float f32x4;

__device__ __forceinline__ float lrelu(float x) { return x >= 0.f ? x : SLOPE * x; }
__device__ __forceinline__ unsigned short f2b(float f) {
  union { float f; unsigned u; } v; v.f = f;
  unsigned r = v.u + 0x7fffu + ((v.u >> 16) & 1u);  // round-to-nearest-even
  return (unsigned short)(r >> 16);
}
__device__ __forceinline__ float b2f(unsigned short u) {
  union { unsigned u; float f; } v; v.u = ((unsigned)u) << 16; return v.f;
}

// ---------------- CSR build ----------------

__global__ __launch_bounds__(256) void count_kernel(const int* __restrict__ dst,
                                                    int* __restrict__ cnt, int nE) {
  int e = blockIdx.x * 256 + threadIdx.x;
  if (e < nE) atomicAdd(&cnt[dst[e]], 1);
}

// phase 1: per-block exclusive scan; rowptr[i] = local exclusive prefix, bsum[b] = block total
__global__ __launch_bounds__(1024) void scan1_kernel(const int* __restrict__ cnt,
                                                     int* __restrict__ rowptr,
                                                     int* __restrict__ bsum, int n) {
  __shared__ int wsum[16];
  const int tid = threadIdx.x;
  const int lane = tid & 63, wid = tid >> 6;
  int i = blockIdx.x * 1024 + tid;
  int v = (i < n) ? cnt[i] : 0;
  int x = v;
#pragma unroll
  for (int off = 1; off < 64; off <<= 1) {
    int y = __shfl_up(x, off, 64);
    if (lane >= off) x += y;
  }
  if (lane == 63) wsum[wid] = x;
  __syncthreads();
  if (tid == 0) {
    int s = 0;
#pragma unroll
    for (int w = 0; w < 16; ++w) { int t = wsum[w]; wsum[w] = s; s += t; }
    bsum[blockIdx.x] = s;
  }
  __syncthreads();
  if (i < n) rowptr[i] = wsum[wid] + x - v;  // local exclusive
}

// phase 2: one wave scans the (<=64) block sums in place (exclusive); rowptr[n] = E
__global__ __launch_bounds__(64) void scan2_kernel(int* __restrict__ bsum, int nb,
                                                   int* __restrict__ rowptr, int n, int E) {
  int lane = threadIdx.x;
  int v = (lane < nb) ? bsum[lane] : 0;
  int x = v;
#pragma unroll
  for (int off = 1; off < 64; off <<= 1) {
    int y = __shfl_up(x, off, 64);
    if (lane >= off) x += y;
  }
  if (lane < nb) bsum[lane] = x - v;  // exclusive
  if (lane == 0) rowptr[n] = E;
}

// phase 3: add block offset; compute dinv; reset cnt (cursor for fill)
__global__ __launch_bounds__(1024) void scan3_kernel(int* __restrict__ cnt,
                                                     int* __restrict__ rowptr,
                                                     const int* __restrict__ bsum,
                                                     float* __restrict__ dinv, int n) {
  int i = blockIdx.x * 1024 + threadIdx.x;
  if (i >= n) return;
  rowptr[i] += bsum[blockIdx.x];
  dinv[i] = rsqrtf((float)cnt[i] + 1.0f);
  cnt[i] = 0;
}

__global__ __launch_bounds__(256) void fill_kernel(const int* __restrict__ src,
                                                   const int* __restrict__ dst,
                                                   const int* __restrict__ rowptr,
                                                   int* __restrict__ cursor,
                                                   const float* __restrict__ dinv,
                                                   int* __restrict__ csr_src,
                                                   float* __restrict__ csr_norm, int nE) {
  int e = blockIdx.x * 256 + threadIdx.x;
  if (e >= nE) return;
  int d = dst[e], s = src[e];
  int pos = rowptr[d] + atomicAdd(&cursor[d], 1);
  csr_src[pos] = s;
  csr_norm[pos] = dinv[s] * dinv[d];
}

// ---------------- weight pack: B-fragment order for mfma 16x16x32 ----------------
// packed[(t*8+c)*64 + lane][j] = W[t*32 + (lane>>4)*8 + j][c*16 + (lane&15)]

__global__ __launch_bounds__(256) void pack_kernel(const float* W0, const float* W1,
                                                   const float* W2, const float* W3,
                                                   const float* W4, const float* W5,
                                                   unsigned short* __restrict__ out) {
  const float* Ws[6] = {W0, W1, W2, W3, W4, W5};
  const float* W = Ws[blockIdx.y];
  int f = blockIdx.x * 256 + threadIdx.x;  // 0..16383
  int j = f & 7, L = (f >> 3) & 63, c = (f >> 9) & 7, t = f >> 12;
  int k = t * 32 + (L >> 4) * 8 + j;
  int n = c * 16 + (L & 15);
  out[(size_t)blockIdx.y * 16384 + f] = f2b(W[k * HH + n]);
}

// ---------------- MFMA GEMM: [nrows,128] @ [128,128] ----------------
// 256 threads = 4 waves; 64 rows/block (16 rows/wave); each wave touches only
// its own 16-row slice of the LDS A-tile.

template <int BIAS, int LEAKY, int RES, int INTERP, int OUT_BF16>
__global__ __launch_bounds__(256) void gemm_mfma(const float* __restrict__ A,
                                                 const unsigned short* __restrict__ Wp,
                                                 const float* __restrict__ bias,
                                                 const float* __restrict__ res,
                                                 const float* __restrict__ gen,
                                                 void* __restrict__ outv, int nrows) {
  __shared__ __align__(16) unsigned short Al[64 * HH];
  const int tid = threadIdx.x;
  const int row0 = blockIdx.x * 64;

  for (int i = tid; i < 2048; i += 256) {
    int r = i >> 5, c = (i & 31) << 2;
    int gr = row0 + r;
    float4 v = make_float4(0.f, 0.f, 0.f, 0.f);
    if (gr < nrows) {
      v = *(const float4*)(A + (size_t)gr * HH + c);
      if (INTERP) {
        float4 g = *(const float4*)(gen + (size_t)gr * HH + c);
        v.x = 0.5f * (v.x + g.x); v.y = 0.5f * (v.y + g.y);
        v.z = 0.5f * (v.z + g.z); v.w = 0.5f * (v.w + g.w);
      }
    }
    ushort4 o;
    o.x = f2b(v.x); o.y = f2b(v.y); o.z = f2b(v.z); o.w = f2b(v.w);
    *(ushort4*)&Al[r * HH + c] = o;
  }
  __syncthreads();

  const int lane = tid & 63, wave = tid >> 6;
  const int m = lane & 15, quad = lane >> 4;
  const int arow = wave * 16 + m;

  f32x4 acc[8];
#pragma unroll
  for (int c = 0; c < 8; ++c) acc[c] = (f32x4){0.f, 0.f, 0.f, 0.f};

  const bf16x8* Wf = (const bf16x8*)Wp;
#pragma unroll
  for (int t = 0; t < 4; ++t) {
    bf16x8 a = *(const bf16x8*)&Al[arow * HH + t * 32 + quad * 8];
#pragma unroll
    for (int c = 0; c < 8; ++c) {
      bf16x8 b = Wf[(t * 8 + c) * 64 + lane];
      acc[c] = __builtin_amdgcn_mfma_f32_16x16x32_bf16(a, b, acc[c], 0, 0, 0);
    }
  }

#pragma unroll
  for (int c = 0; c < 8; ++c) {
    int col = c * 16 + m;
    float bv = BIAS ? bias[col] : 0.f;
#pragma unroll
    for (int g = 0; g < 4; ++g) {
      int row = row0 + wave * 16 + quad * 4 + g;
      if (row < nrows) {
        float v = acc[c][g] + bv;
        if (RES) v += res[(size_t)row * HH + col];
        if (LEAKY) v = lrelu(v);
        if (OUT_BF16) ((unsigned short*)outv)[(size_t)row * HH + col] = f2b(v);
        else ((float*)outv)[(size_t)row * HH + col] = v;
      }
    }
  }
}

// ---------------- fused double GEMM: out = leaky(leaky(A'@W1+b1)@W2+b2 (+res)) ----------------
// A' = INTERP ? 0.5*(A+gen) : A. Intermediate stays in LDS as bf16 (no global round-trip).
// Each wave owns its 16-row LDS slice end-to-end => no inter-stage __syncthreads.

template <int INTERP, int RES2>
__global__ __launch_bounds__(256) void gemm2_mfma(const float* __restrict__ A,
                                                  const unsigned short* __restrict__ Wp1,
                                                  const unsigned short* __restrict__ Wp2,
                                                  const float* __restrict__ bias1,
                                                  const float* __restrict__ bias2,
                                                  const float* __restrict__ res,
                                                  const float* __restrict__ gen,
                                                  float* __restrict__ out, int nrows) {
  __shared__ __align__(16) unsigned short Al[64 * HH];
  const int tid = threadIdx.x;
  const int row0 = blockIdx.x * 64;

  for (int i = tid; i < 2048; i += 256) {
    int r = i >> 5, c = (i & 31) << 2;
    int gr = row0 + r;
    float4 v = make_float4(0.f, 0.f, 0.f, 0.f);
    if (gr < nrows) {
      v = *(const float4*)(A + (size_t)gr * HH + c);
      if (INTERP) {
        float4 g = *(const float4*)(gen + (size_t)gr * HH + c);
        v.x = 0.5f * (v.x + g.x); v.y = 0.5f * (v.y + g.y);
        v.z = 0.5f * (v.z + g.z); v.w = 0.5f * (v.w + g.w);
      }
    }
    ushort4 o;
    o.x = f2b(v.x); o.y = f2b(v.y); o.z = f2b(v.z); o.w = f2b(v.w);
    *(ushort4*)&Al[r * HH + c] = o;
  }
  __syncthreads();

  const int lane = tid & 63, wave = tid >> 6;
  const int m = lane & 15, quad = lane >> 4;
  const int arow = wave * 16 + m;

  f32x4 acc[8];
  const bf16x8* Wf1 = (const bf16x8*)Wp1;
  const bf16x8* Wf2 = (const bf16x8*)Wp2;

  // ---- stage 1 ----
#pragma unroll
  for (int c = 0; c < 8; ++c) acc[c] = (f32x4){0.f, 0.f, 0.f, 0.f};
#pragma unroll
  for (int t = 0; t < 4; ++t) {
    bf16x8 a = *(const bf16x8*)&Al[arow * HH + t * 32 + quad * 8];
#pragma unroll
    for (int c = 0; c < 8; ++c) {
      bf16x8 b = Wf1[(t * 8 + c) * 64 + lane];
      acc[c] = __builtin_amdgcn_mfma_f32_16x16x32_bf16(a, b, acc[c], 0, 0, 0);
    }
  }
  // epilogue 1: bias + leaky -> bf16 back into this wave's LDS slice
#pragma unroll
  for (int c = 0; c < 8; ++c) {
    int col = c * 16 + m;
    float bv = bias1[col];
#pragma unroll
    for (int g = 0; g < 4; ++g) {
      int lrow = wave * 16 + quad * 4 + g;
      Al[lrow * HH + col] = f2b(lrelu(acc[c][g] + bv));
    }
  }

  // ---- stage 2 ----
#pragma unroll
  for (int c = 0; c < 8; ++c) acc[c] = (f32x4){0.f, 0.f, 0.f, 0.f};
#pragma unroll
  for (int t = 0; t < 4; ++t) {
    bf16x8 a = *(const bf16x8*)&Al[arow * HH + t * 32 + quad * 8];
#pragma unroll
    for (int c = 0; c < 8; ++c) {
      bf16x8 b = Wf2[(t * 8 + c) * 64 + lane];
      acc[c] = __builtin_amdgcn_mfma_f32_16x16x32_bf16(a, b, acc[c], 0, 0, 0);
    }
  }
#pragma unroll
  for (int c = 0; c < 8; ++c) {
    int col = c * 16 + m;
    float bv = bias2[col];
#pragma unroll
    for (int g = 0; g < 4; ++g) {
      int row = row0 + wave * 16 + quad * 4 + g;
      if (row < nrows) {
        float v = acc[c][g] + bv;
        if (RES2) v += res[(size_t)row * HH + col];
        out[(size_t)row * HH + col] = lrelu(v);
      }
    }
  }
}

// ---------------- fused aggregate (bf16 gather) + self + bias (+res) + leaky ----------------

template <int RES>
__global__ __launch_bounds__(256) void agg_kernel(const unsigned short* __restrict__ h,
                                                  const int* __restrict__ rowptr,
                                                  const int* __restrict__ csr_src,
                                                  const float* __restrict__ csr_norm,
                                                  const float* __restrict__ dinv,
                                                  const float* __restrict__ bias,
                                                  const float* __restrict__ res,
                                                  float* __restrict__ out, int n) {
  int node = blockIdx.x * 4 + (threadIdx.x >> 6);
  if (node >= n) return;
  int lane = threadIdx.x & 63;
  int c = lane << 1;
  int j = rowptr[node], end = rowptr[node + 1];
  float ax = 0.f, ay = 0.f;
  for (; j + 2 <= end; j += 2) {
    int s0 = csr_src[j], s1 = csr_src[j + 1];
    float n0 = csr_norm[j], n1 = csr_norm[j + 1];
    ushort2 r0 = *(const ushort2*)(h + (size_t)s0 * HH + c);
    ushort2 r1 = *(const ushort2*)(h + (size_t)s1 * HH + c);
    ax = fmaf(b2f(r0.x), n0, ax); ay = fmaf(b2f(r0.y), n0, ay);
    ax = fmaf(b2f(r1.x), n1, ax); ay = fmaf(b2f(r1.y), n1, ay);
  }
  if (j < end) {
    int s0 = csr_src[j];
    float n0 = csr_norm[j];
    ushort2 r0 = *(const ushort2*)(h + (size_t)s0 * HH + c);
    ax = fmaf(b2f(r0.x), n0, ax); ay = fmaf(b2f(r0.y), n0, ay);
  }
  float di = dinv[node], d2 = di * di;
  ushort2 hs = *(const ushort2*)(h + (size_t)node * HH + c);
  float2 b = *(const float2*)(bias + c);
  float ox = ax + b2f(hs.x) * d2 + b.x;
  float oy = ay + b2f(hs.y) * d2 + b.y;
  if (RES) {
    float2 r = *(const float2*)(res + (size_t)node * HH + c);
    ox += r.x; oy += r.y;
  }
  ox = lrelu(ox); oy = lrelu(oy);
  *(float2*)(out + (size_t)node * HH + c) = make_float2(ox, oy);
}

// ---------------- launcher ----------------

extern "C" void kernel_launch(void* const* d_in, const int* in_sizes, int n_in,
                              void* d_out, int out_size, void* d_ws, size_t ws_size,
                              hipStream_t stream) {
  const float* x   = (const float*)d_in[0];
  const int* ei    = (const int*)d_in[1];
  const float* gen = (const float*)d_in[2];
  const float* Wc1 = (const float*)d_in[3];
  const float* bc1 = (const float*)d_in[4];
  const float* Wc2 = (const float*)d_in[5];
  const float* bc2 = (const float*)d_in[6];
  const float* Wm1 = (const float*)d_in[7];
  const float* bm1 = (const float*)d_in[8];
  const float* Wm2 = (const float*)d_in[9];
  const float* bm2 = (const float*)d_in[10];
  const float* Wp1 = (const float*)d_in[11];
  const float* bp1 = (const float*)d_in[12];
  const float* Wp2 = (const float*)d_in[13];
  const float* bp2 = (const float*)d_in[14];

  const int N = in_sizes[0] / HH;
  const int E = in_sizes[1] / 2;
  const int* src = ei;
  const int* dst = ei + E;

  char* ws = (char*)d_ws;
  size_t off = 0;
  auto alloc = [&](size_t bytes) { void* p = ws + off; off += (bytes + 255) & ~(size_t)255; return p; };
  float* dinv            = (float*)alloc((size_t)N * 4);
  int*   rowptr          = (int*)  alloc((size_t)(N + 1) * 4);
  int*   cursor          = (int*)  alloc((size_t)N * 4);
  int*   bsum            = (int*)  alloc((size_t)64 * 4);
  int*   csr_src         = (int*)  alloc((size_t)E * 4);
  float* csr_norm        = (float*)alloc((size_t)E * 4);
  unsigned short* h_bf   = (unsigned short*)alloc((size_t)N * HH * 2);
  float* f1              = (float*)alloc((size_t)N * HH * 4);
  unsigned short* packed = (unsigned short*)alloc((size_t)6 * 16384 * 2);
  float* fOut = (float*)d_out;

  const int gblocks = (N + 63) / 64;
  const int eblocks = (E + 255) / 256;
  const int ablocks = (N + 3) / 4;
  const int sblocks = (N + 1023) / 1024;  // <= 64 for N <= 65536

  // weight packing (6 weights x 16384 frag elements)
  pack_kernel<<<dim3(64, 6), 256, 0, stream>>>(Wc1, Wc2, Wm1, Wm2, Wp1, Wp2, packed);

  // CSR build
  hipMemsetAsync(cursor, 0, (size_t)N * 4, stream);
  count_kernel<<<eblocks, 256, 0, stream>>>(dst, cursor, E);
  scan1_kernel<<<sblocks, 1024, 0, stream>>>(cursor, rowptr, bsum, N);
  scan2_kernel<<<1, 64, 0, stream>>>(bsum, sblocks, rowptr, N, E);
  scan3_kernel<<<sblocks, 1024, 0, stream>>>(cursor, rowptr, bsum, dinv, N);
  fill_kernel<<<eblocks, 256, 0, stream>>>(src, dst, rowptr, cursor, dinv, csr_src, csr_norm, E);

  // conv1: h_bf = bf16(x @ Wc1); f1 = leaky(agg + self + bc1)
  gemm_mfma<0, 0, 0, 0, 1><<<gblocks, 256, 0, stream>>>(x, packed + 0 * 16384, nullptr, nullptr, nullptr, h_bf, N);
  agg_kernel<0><<<ablocks, 256, 0, stream>>>(h_bf, rowptr, csr_src, csr_norm, dinv, bc1, nullptr, f1, N);

  // conv2: h_bf = bf16(f1 @ Wc2); f1 = leaky(agg + self + bc2 + f1)
  gemm_mfma<0, 0, 0, 0, 1><<<gblocks, 256, 0, stream>>>(f1, packed + 1 * 16384, nullptr, nullptr, nullptr, h_bf, N);
  agg_kernel<1><<<ablocks, 256, 0, stream>>>(h_bf, rowptr, csr_src, csr_norm, dinv, bc2, f1, f1, N);

  // MLP (fused pair): f1 = h3 = leaky(leaky(f1@Wm1+bm1)@Wm2 + bm2 + f1)
  gemm2_mfma<0, 1><<<gblocks, 256, 0, stream>>>(f1, packed + 2 * 16384, packed + 3 * 16384,
                                                bm1, bm2, f1, nullptr, f1, N);

  // proj (fused pair, interp folded in): d_out = leaky(leaky((0.5*(f1+gen))@Wp1+bp1)@Wp2+bp2)
  gemm2_mfma<1, 0><<<gblocks, 256, 0, stream>>>(f1, packed + 4 * 16384, packed + 5 * 16384,
                                                bp1, bp2, nullptr, gen, fOut, N);
}